// Round 4
// baseline (340.836 us; speedup 1.0000x reference)
//
#include <hip/hip_runtime.h>

// ---------- types ----------
typedef short  short8 __attribute__((ext_vector_type(8)));
typedef short  sv4    __attribute__((ext_vector_type(4)));   // 'short4' collides with HIP typedef
typedef __bf16 bf16x8 __attribute__((ext_vector_type(8)));
typedef float  f32x4  __attribute__((ext_vector_type(4)));

__device__ __forceinline__ float bf2f(short s) {
    unsigned u = ((unsigned)(unsigned short)s) << 16;
    return __builtin_bit_cast(float, u);
}
__device__ __forceinline__ short f2bf(float f) {
    unsigned u = __builtin_bit_cast(unsigned, f);
    u += 0x7fffu + ((u >> 16) & 1u);   // RNE
    return (short)(u >> 16);
}
__device__ __forceinline__ f32x4 mfma16(short8 a, short8 b, f32x4 c) {
    return __builtin_amdgcn_mfma_f32_16x16x32_bf16(
        __builtin_bit_cast(bf16x8, a), __builtin_bit_cast(bf16x8, b), c, 0, 0, 0);
}
// async global->LDS, 16B/lane; LDS dest = wave-uniform base + lane*16
__device__ __forceinline__ void gl16(const short* g, short* l) {
    __builtin_amdgcn_global_load_lds(
        (const __attribute__((address_space(1))) void*)g,
        (__attribute__((address_space(3))) void*)l, 16, 0, 0);
}

// Geometry: B=8, H=W=64, C=256, CQ=64
// x NHWC: idx = ((b*64+h)*64+w)*256 + c ; planar [b][c][h][w]

// ---------- 0. dtype detect ----------
__global__ __launch_bounds__(256) void detect_k(const short* x, int* flag)
{
    __shared__ int red[256];
    int t = threadIdx.x;
    int cnt = 0;
    for (int i = t; i < 4096; i += 256) {
        int e = (x[2 * i] >> 7) & 0xFF;
        cnt += (e >= 100 && e <= 140) ? 1 : 0;
    }
    red[t] = cnt; __syncthreads();
    for (int s = 128; s > 0; s >>= 1) { if (t < s) red[t] += red[t + s]; __syncthreads(); }
    if (t == 0) *flag = (red[0] < 3277) ? 1 : 0;   // 1 => inputs are fp32
}

// ---------- 1a. x -> bf16 ----------
__global__ __launch_bounds__(256) void convert_x(const void* x, short* xb, const int* flagp)
{
    int f32 = *flagp;
    size_t i = ((size_t)blockIdx.x * 256 + threadIdx.x) * 8;
    short8 v;
    if (f32) {
        const float* fs = (const float*)x + i;
        f32x4 a = *(const f32x4*)fs;
        f32x4 b = *(const f32x4*)(fs + 4);
#pragma unroll
        for (int l = 0; l < 4; l++) { v[l] = f2bf(a[l]); v[4 + l] = f2bf(b[l]); }
    } else {
        v = *(const short8*)((const short*)x + i);
    }
    *(short8*)(xb + i) = v;
}

// ---------- 1b. weight repack + bias concat + zero block ----------
struct Ptrs {
    const void *wq, *wq1, *wq2, *wq3, *wq4, *wk, *wv;
    const void *bq, *bq1, *bq2, *bq3, *bq4, *bk, *bv, *gm;
};

__global__ __launch_bounds__(256) void convert_k(Ptrs P, short* wp, short* bb, const int* flagp)
{
    int f32 = *flagp;
    int idx = blockIdx.x * 256 + threadIdx.x;
    if (idx < 1179648) {
        const void* src; int Cout, base;
        if      (idx <   16384) { src = P.wq;  Cout =  64; base = 0; }
        else if (idx <  163840) { src = P.wq1; Cout =  64; base = 16384; }
        else if (idx <  311296) { src = P.wq2; Cout =  64; base = 163840; }
        else if (idx <  458752) { src = P.wq3; Cout =  64; base = 311296; }
        else if (idx <  524288) { src = P.wq4; Cout = 256; base = 458752; }
        else if (idx < 1114112) { src = P.wk;  Cout = 256; base = 524288; }
        else                    { src = P.wv;  Cout = 256; base = 1114112; }
        int rem = idx - base;
        int t   = rem / (Cout * 256);
        int r2  = rem - t * Cout * 256;
        int co  = r2 >> 8;
        int ci  = r2 & 255;
        int si  = (t * 256 + ci) * Cout + co;
        wp[idx] = f32 ? f2bf(((const float*)src)[si]) : ((const short*)src)[si];
    } else if (idx < 1179648 + 1280) {
        int j = idx - 1179648;
        if (j < 1025) {
            const void* src; int off;
            if      (j <   64) { src = P.bq;  off = j; }
            else if (j <  128) { src = P.bq1; off = j - 64; }
            else if (j <  192) { src = P.bq2; off = j - 128; }
            else if (j <  256) { src = P.bq3; off = j - 192; }
            else if (j <  512) { src = P.bq4; off = j - 256; }
            else if (j <  768) { src = P.bk;  off = j - 512; }
            else if (j < 1024) { src = P.bv;  off = j - 768; }
            else               { src = P.gm;  off = 0; }
            bb[j] = f32 ? f2bf(((const float*)src)[off]) : ((const short*)src)[off];
        } else if (j >= 1032) {
            bb[j] = 0;                 // 496-B zero block for OOB staging
        }
    }
}

// ---------- 2a. conv8: fine 4-phase pipelined 3x3 dil=1 256->256 implicit GEMM ----------
// BM=128 x BN=256, BK=64, 8 waves (2M x 4N, 64x64 each), ring-3 LDS (144 KB),
// stage issued 2 K-steps ahead. Per K-step, 4 phases:
//   { ds_read B-quadrant (+ all A in phase 0) | issue 2 gl16 of step s+2
//     -> barrier -> setprio(1) 8xMFMA setprio(0) -> barrier }
// vmcnt(6) only at phase 3 (drains step s+1's 6 oldest loads; 6 stay in
// flight) -- never 0 in the main loop.  LDS chunk c of row r at c^(r&7).
struct C8Job {
    const short* src;   // NHWC bf16, Cin=256
    short*       dst;
    const short* wpk;   // packed [t][co][ci], tap stride 65536
    const short* bias;  // 256
    int outmode;        // 0: NHWC  2: planar [b][c][h][w]
};

__global__ __launch_bounds__(512, 2) void conv8_tile(C8Job J, const short* zp)
{
    __shared__ short Sh[73728];   // 3 x (A 8192 + B 16384) shorts = 144 KB
    int tid  = threadIdx.x;
    int wid  = tid >> 6, lane = tid & 63;
    int bid  = blockIdx.x;
    int Mtile = (bid & 7) * 32 + (bid >> 3);    // bijective XCD swizzle (256 blocks)
    int p0 = Mtile * 128;
    int b  = p0 >> 12;
    int h0 = (p0 >> 6) & 63;

    int lrow = lane & 15, quad = lane >> 4;
    int lr8  = lane >> 3;
    int cl   = (lane & 7) ^ (lr8 & 7);          // logical chunk this lane stages
    int m_base = (wid >> 2) * 64;
    int n_base = (wid & 3) * 64;

    // A roots (center tap) + 9-bit tap-validity masks (2 issues/wave)
    const short* aroot[2]; unsigned vmask[2];
#pragma unroll
    for (int jj = 0; jj < 2; jj++) {
        int m  = (jj * 8 + wid) * 8 + lr8;      // 0..127
        int hh = h0 + (m >> 6);
        int ww = m & 63;
        aroot[jj] = J.src + (((b * 64 + hh) * 64 + ww) * 256 + cl * 8);
        unsigned msk = 0;
#pragma unroll
        for (int t = 0; t < 9; ++t) {
            int dy = t / 3 - 1, dx = t % 3 - 1;
            bool v = ((unsigned)(hh + dy) < 64u) && ((unsigned)(ww + dx) < 64u);
            msk |= (v ? 1u : 0u) << t;
        }
        vmask[jj] = msk;
    }
    // B roots (4 issues/wave)
    const short* wroot[4];
#pragma unroll
    for (int jj = 0; jj < 4; jj++) {
        int n = (jj * 8 + wid) * 8 + lr8;       // 0..255
        wroot[jj] = J.wpk + n * 256 + cl * 8;
    }

    auto STAGE_A = [&](int step, short* bufb) {
        int t = step >> 2, s4 = step & 3;
        int dy = t / 3 - 1, dx = t % 3 - 1;
        int tdel = (dy * 64 + dx) * 256 + s4 * 64;
#pragma unroll
        for (int jj = 0; jj < 2; jj++) {
            const short* p = ((vmask[jj] >> t) & 1u) ? (aroot[jj] + tdel) : (zp + s4 * 64);
            gl16(p, bufb + (jj * 8 + wid) * 512);
        }
    };
    auto STAGE_B = [&](int step, short* bufb, int half) {
        int t = step >> 2, s4 = step & 3;
#pragma unroll
        for (int jj = half * 2; jj < half * 2 + 2; jj++)
            gl16(wroot[jj] + t * 65536 + s4 * 64, bufb + 8192 + (jj * 8 + wid) * 512);
    };

    // per-lane fragment offsets
    int pcj0 = ((quad    ) ^ (lrow & 7)) * 8;
    int pcj1 = ((4 + quad) ^ (lrow & 7)) * 8;

    f32x4 acc[4][4] = {};
    // prologue: fully stage steps 0 and 1 (12 loads in flight)
    STAGE_A(0, Sh);          STAGE_B(0, Sh, 0);          STAGE_B(0, Sh, 1);
    STAGE_A(1, Sh + 24576);  STAGE_B(1, Sh + 24576, 0);  STAGE_B(1, Sh + 24576, 1);
    // drain step 0's loads (oldest 6); step 1's stay in flight
    asm volatile("s_waitcnt vmcnt(6)" ::: "memory");
    __builtin_amdgcn_sched_barrier(0);
    __builtin_amdgcn_s_barrier();
    __builtin_amdgcn_sched_barrier(0);

    int cur = 0;
    for (int s = 0; s < 36; ++s) {
        int nxt2 = cur + 2; if (nxt2 >= 3) nxt2 -= 3;
        short* bufc = Sh + cur * 24576;
        short* bufn = Sh + nxt2 * 24576;
        bool stg = (s < 34);

        short8 a4[4][2];
        // ================= phase 0: all A + B-quadrant 0 ==================
#pragma unroll
        for (int mi = 0; mi < 4; mi++) {
            a4[mi][0] = *(const short8*)(bufc + (m_base + mi * 16 + lrow) * 64 + pcj0);
            a4[mi][1] = *(const short8*)(bufc + (m_base + mi * 16 + lrow) * 64 + pcj1);
        }
        {
            short8 b0 = *(const short8*)(bufc + 8192 + (n_base + lrow) * 64 + pcj0);
            short8 b1 = *(const short8*)(bufc + 8192 + (n_base + lrow) * 64 + pcj1);
            if (stg) STAGE_A(s + 2, bufn);
            __builtin_amdgcn_sched_barrier(0);
            __builtin_amdgcn_s_barrier();
            __builtin_amdgcn_sched_barrier(0);
            __builtin_amdgcn_s_setprio(1);
#pragma unroll
            for (int mi = 0; mi < 4; mi++) {
                acc[mi][0] = mfma16(a4[mi][0], b0, acc[mi][0]);
                acc[mi][0] = mfma16(a4[mi][1], b1, acc[mi][0]);
            }
            __builtin_amdgcn_s_setprio(0);
            __builtin_amdgcn_sched_barrier(0);
            __builtin_amdgcn_s_barrier();
            __builtin_amdgcn_sched_barrier(0);
        }
        // ================= phases 1..3: B-quadrant q ==================
#pragma unroll
        for (int q = 1; q < 4; ++q) {
            short8 b0 = *(const short8*)(bufc + 8192 + (n_base + q * 16 + lrow) * 64 + pcj0);
            short8 b1 = *(const short8*)(bufc + 8192 + (n_base + q * 16 + lrow) * 64 + pcj1);
            if (q == 1 && stg) STAGE_B(s + 2, bufn, 0);
            if (q == 2 && stg) STAGE_B(s + 2, bufn, 1);
            __builtin_amdgcn_sched_barrier(0);
            __builtin_amdgcn_s_barrier();
            __builtin_amdgcn_sched_barrier(0);
            __builtin_amdgcn_s_setprio(1);
#pragma unroll
            for (int mi = 0; mi < 4; mi++) {
                acc[mi][q] = mfma16(a4[mi][0], b0, acc[mi][q]);
                acc[mi][q] = mfma16(a4[mi][1], b1, acc[mi][q]);
            }
            __builtin_amdgcn_s_setprio(0);
            __builtin_amdgcn_sched_barrier(0);
            if (q < 3) {
                __builtin_amdgcn_s_barrier();
                __builtin_amdgcn_sched_barrier(0);
            }
        }
        // ---- step boundary: drain next step's loads (counted, never 0 mid-loop)
        if (s <= 33)      { asm volatile("s_waitcnt vmcnt(6)" ::: "memory"); }
        else if (s == 34) { asm volatile("s_waitcnt vmcnt(0)" ::: "memory"); }
        __builtin_amdgcn_sched_barrier(0);
        __builtin_amdgcn_s_barrier();
        __builtin_amdgcn_sched_barrier(0);
        cur += 1; if (cur >= 3) cur -= 3;
    }

    int rq = quad * 4;
#pragma unroll
    for (int ni = 0; ni < 4; ni++) {
        int co = n_base + ni * 16 + lrow;
        float bv = bf2f(J.bias[co]);
        if (J.outmode == 0) {
#pragma unroll
            for (int mi = 0; mi < 4; mi++) {
                int pb = p0 + m_base + mi * 16 + rq;
#pragma unroll
                for (int r = 0; r < 4; r++)
                    J.dst[(size_t)(pb + r) * 256 + co] = f2bf(acc[mi][ni][r] + bv);
            }
        } else {                                 // planar [b][co][h][w]
            int hw = h0 + (m_base >> 6);
            short* row = J.dst + ((size_t)(b * 256 + co) * 64 + hw) * 64;
#pragma unroll
            for (int mi = 0; mi < 4; mi++) {
                sv4 o;
#pragma unroll
                for (int r = 0; r < 4; r++) o[r] = f2bf(acc[mi][ni][r] + bv);
                *(sv4*)(row + mi * 16 + rq) = o;
            }
        }
    }
}

// ---------- 2b. conv: block-tiled implicit GEMM (small/mid jobs), BK=64 ----------
struct CJob {
    const short* src;   // NHWC bf16, Cin=256
    short*       dst;
    const short* wpk;   // packed [t][co][ci]
    const short* bias;
    int Cout;           // 64 or 256
    int dil;
    int ntaps;          // 1 or 9
    int coff;           // dst channel offset (outmode 0)
    int outmode;        // 0: NHWC+coff  2: planar [b][c][h][w]
                        // 3: planar-T [b][c][w][h] via TRANSPOSED SOURCE (1x1 only)
};
struct CTable { CJob j[6]; int end[6]; };

template<int NA, int NB, int BOFS, int WSTEP>
__device__ __forceinline__ void conv_loop(
    const short* src, const short* wpk, int ntaps, int dil,
    const short* zp, short* Sh,
    int wave, int lr8, int cl, int h0, int b, int nt0, int srcT,
    int m_base, int n_base, int lrow, int pc0, int pc1,
    f32x4 (&acc)[4][4])
{
    const short* abase[NA];
    unsigned     vm[NA];
    const short* bbase[NB];
#pragma unroll
    for (int jj = 0; jj < NA; jj++) {
        int m  = (jj * 4 + wave) * 8 + lr8;
        int hh = srcT ? (m & 63) : (h0 + (m >> 6));
        int ww = srcT ? (h0 + (m >> 6)) : (m & 63);
        abase[jj] = src + (((b * 64 + hh) * 64 + ww) * 256 + cl * 8);
        unsigned msk = 1u;
        if (ntaps == 9) {
            msk = 0u;
#pragma unroll
            for (int t = 0; t < 9; ++t) {
                int tr = (t >= 6) ? 2 : ((t >= 3) ? 1 : 0);
                int dy = (tr - 1) * dil, dx = (t - tr * 3 - 1) * dil;
                bool v = ((unsigned)(hh + dy) < 64u) && ((unsigned)(ww + dx) < 64u);
                msk |= (v ? 1u : 0u) << t;
            }
        }
        vm[jj] = msk;
    }
#pragma unroll
    for (int jj = 0; jj < NB; jj++) {
        int n = (jj * 4 + wave) * 8 + lr8;
        bbase[jj] = wpk + (nt0 + n) * 256 + cl * 8;
    }

    int prevdel = 0;
    for (int t = 0; t < ntaps; ++t) {
        int dy = 0, dx = 0;
        if (ntaps == 9) {
            int tr = (t >= 6) ? 2 : ((t >= 3) ? 1 : 0);
            dy = (tr - 1) * dil;
            dx = (t - tr * 3 - 1) * dil;
        }
        int tdel = (dy * 64 + dx) * 256;
        int step = tdel - prevdel; prevdel = tdel;
        const short* pA[NA];
#pragma unroll
        for (int jj = 0; jj < NA; jj++) {
            abase[jj] += step;
            pA[jj] = ((vm[jj] >> t) & 1u) ? abase[jj] : zp;
        }
#pragma unroll
        for (int s4 = 0; s4 < 4; ++s4) {
#pragma unroll
            for (int jj = 0; jj < NA; jj++)
                gl16(pA[jj] + s4 * 64, Sh + (jj * 4 + wave) * 512);
#pragma unroll
            for (int jj = 0; jj < NB; jj++)
                gl16(bbase[jj] + s4 * 64, Sh + BOFS + (jj * 4 + wave) * 512);
            __syncthreads();
#pragma unroll
            for (int j = 0; j < 2; j++) {
                int pc = j ? pc1 : pc0;
                short8 a4[4], b4[4];
#pragma unroll
                for (int mi = 0; mi < 4; mi++)
                    a4[mi] = *(const short8*)(Sh + (m_base + mi * 16 + lrow) * 64 + pc);
#pragma unroll
                for (int ni = 0; ni < 4; ni++)
                    b4[ni] = *(const short8*)(Sh + BOFS + (n_base + ni * 16 + lrow) * 64 + pc);
#pragma unroll
                for (int mi = 0; mi < 4; mi++)
#pragma unroll
                    for (int ni = 0; ni < 4; ni++)
                        acc[mi][ni] = mfma16(a4[mi], b4[ni], acc[mi][ni]);
            }
            __syncthreads();
        }
#pragma unroll
        for (int jj = 0; jj < NB; jj++) bbase[jj] += WSTEP;
    }
}

__global__ __launch_bounds__(256, 3) void conv_tile(CTable T, const short* zp)
{
    __shared__ short Sh[20480];   // 40 KB: A at 0, B at BOFS
    int tid = threadIdx.x;
    int bid = blockIdx.x;
    int ji = 0;
    while (ji < 5 && bid >= T.end[ji]) ji++;
    CJob J = T.j[ji];
    int s0  = ji ? T.end[ji - 1] : 0;
    int seg = T.end[ji] - s0;
    int lb  = bid - s0;
    int g   = (lb & 7) * (seg >> 3) + (lb >> 3);

    int big   = (J.Cout == 256);
    int BM    = big ? 128 : 256;
    int ntile = big ? (g & 1) : 0;
    int Mtile = big ? (g >> 1) : g;
    int p0 = Mtile * BM;
    int b  = p0 >> 12;
    int h0 = (p0 >> 6) & 63;
    int nt0  = ntile * 128;
    int srcT = (J.outmode == 3);

    int wave = tid >> 6, lane = tid & 63;
    int lrow = lane & 15, quad = lane >> 4;
    int m_base = big ? (wave & 1) * 64 : wave * 64;
    int n_base = big ? (wave >> 1) * 64 : 0;

    int lr8 = lane >> 3;
    int cl  = (lane & 7) ^ (lr8 & 7);

    int pc0 = ((quad     ^ (lrow & 7)) * 8);
    int pc1 = (((4 + quad) ^ (lrow & 7)) * 8);

    f32x4 acc[4][4] = {};
    if (big)
        conv_loop<4, 4, 8192, 65536>(J.src, J.wpk, J.ntaps, J.dil, zp, Sh,
                                     wave, lr8, cl, h0, b, nt0, srcT,
                                     m_base, n_base, lrow, pc0, pc1, acc);
    else
        conv_loop<8, 2, 16384, 16384>(J.src, J.wpk, J.ntaps, J.dil, zp, Sh,
                                      wave, lr8, cl, h0, b, nt0, srcT,
                                      m_base, n_base, lrow, pc0, pc1, acc);

    int rq = quad * 4;
#pragma unroll
    for (int ni = 0; ni < 4; ni++) {
        int co = nt0 + n_base + ni * 16 + lrow;
        float bv = bf2f(J.bias[co]);
        if (J.outmode == 0) {
#pragma unroll
            for (int mi = 0; mi < 4; mi++) {
                int pb = p0 + m_base + mi * 16 + rq;
#pragma unroll
                for (int r = 0; r < 4; r++)
                    J.dst[(size_t)(pb + r) * 256 + J.coff + co] = f2bf(acc[mi][ni][r] + bv);
            }
        } else {
            int hw = h0 + (m_base >> 6);
            short* row = J.dst + ((size_t)(b * 256 + co) * 64 + hw) * 64;
#pragma unroll
            for (int mi = 0; mi < 4; mi++) {
                sv4 o;
#pragma unroll
                for (int r = 0; r < 4; r++) o[r] = f2bf(acc[mi][ni][r] + bv);
                *(sv4*)(row + mi * 16 + rq) = o;
            }
        }
    }
}

// ---------- 3. energy: Et[b,c,w,i] = sum_j kp[b,c,i,j] * qp[b,c,w,j] ----------
__global__ __launch_bounds__(256) void energy_mfma(const short* qp, const short* kp, float* Et)
{
    int wid  = threadIdx.x >> 6;
    int lane = threadIdx.x & 63;
    int g = blockIdx.x * 4 + wid;           // 0..2047
    int b = g >> 8, c = g & 255;
    int lrow = lane & 15;
    int q8   = (lane >> 4) << 3;
    const short* qb = qp + (size_t)(b * 256 + c) * 4096;
    const short* kb = kp + (size_t)(b * 256 + c) * 4096;

    f32x4 acc[4][4] = {};
#pragma unroll
    for (int ks = 0; ks < 2; ++ks) {
        int j0 = ks * 32 + q8;
        short8 A[4], Bv[4];
#pragma unroll
        for (int mi = 0; mi < 4; mi++)
            A[mi] = *(const short8*)(qb + (size_t)(mi * 16 + lrow) * 64 + j0);
#pragma unroll
        for (int ni = 0; ni < 4; ni++)
            Bv[ni] = *(const short8*)(kb + (size_t)(ni * 16 + lrow) * 64 + j0);
#pragma unroll
        for (int mi = 0; mi < 4; mi++)
#pragma unroll
            for (int ni = 0; ni < 4; ni++)
                acc[mi][ni] = mfma16(A[mi], Bv[ni], acc[mi][ni]);
    }
    int rq = (lane >> 4) * 4;
#pragma unroll
    for (int mi = 0; mi < 4; mi++)
#pragma unroll
        for (int r = 0; r < 4; r++) {
            int w = mi * 16 + rq + r;
            float* row = Et + ((size_t)(b * 256 + c) * 64 + w) * 64;
#pragma unroll
            for (int ni = 0; ni < 4; ni++)
                row[ni * 16 + lrow] = acc[mi][ni][r];
        }
}

// ---------- 4. softmax over c ----------
__global__ __launch_bounds__(256) void softmax_k(const float* Et, short* att)
{
    __shared__ float S[256 * 33];
    __shared__ float red[256];
    __shared__ float sm[256];
    int t  = threadIdx.x;
    int b  = blockIdx.x >> 7;
    int a  = (blockIdx.x >> 1) & 63;
    int jh = blockIdx.x & 1;

    const float* row = Et + ((size_t)(b * 256 + t) * 64 + a) * 64 + jh * 32;
#pragma unroll
    for (int jj = 0; jj < 32; jj += 4) {
        f32x4 v = *(const f32x4*)(row + jj);
#pragma unroll
        for (int l = 0; l < 4; l++) S[t * 33 + jj + l] = v[l];
    }
    __syncthreads();

    int tj = t & 31, tg = t >> 5;
    float m = -1e30f;
#pragma unroll
    for (int cc = 0; cc < 32; ++cc) m = fmaxf(m, S[(tg * 32 + cc) * 33 + tj]);
    red[t] = m;
    __syncthreads();
    if (tg == 0) {
        float mm = red[tj];
#pragma unroll
        for (int gg = 1; gg < 8; ++gg) mm = fmaxf(mm, red[gg * 32 + tj]);
        red[tj] = mm;
    }
    __syncthreads();
    float M = red[tj];
    float s = 0.f;
#pragma unroll
    for (int cc = 0; cc < 32; ++cc) {
        int id = (tg * 32 + cc) * 33 + tj;
        float e = __expf(S[id] - M);
        S[id] = e; s += e;
    }
    sm[t] = s;
    __syncthreads();
    if (tg == 0) {
        float ss = sm[tj];
#pragma unroll
        for (int gg = 1; gg < 8; ++gg) ss += sm[gg * 32 + tj];
        sm[tj] = 1.0f / ss;
    }
    __syncthreads();

    short* orow = att + ((size_t)(b * 256 + t) * 64 + a) * 64 + jh * 32;
#pragma unroll
    for (int jj = 0; jj < 32; jj += 8) {
        short8 o;
#pragma unroll
        for (int l = 0; l < 8; l++) o[l] = f2bf(S[t * 33 + jj + l] * sm[jj + l]);
        *(short8*)(orow + jj) = o;
    }
}

// ---------- 5. out: G[b,c,d,a] = sum_j vp[b,c,d,j] * Att[b,c,a,j] ----------
__global__ __launch_bounds__(256) void out_mfma(const short* vp, const short* att, short* G)
{
    int wid  = threadIdx.x >> 6;
    int lane = threadIdx.x & 63;
    int g = blockIdx.x * 4 + wid;
    int b = g >> 8, c = g & 255;
    int lrow = lane & 15;
    int q8   = (lane >> 4) << 3;
    const short* vb = vp  + (size_t)(b * 256 + c) * 4096;
    const short* ab = att + (size_t)(b * 256 + c) * 4096;

    f32x4 acc[4][4] = {};
#pragma unroll
    for (int ks = 0; ks < 2; ++ks) {
        int j0 = ks * 32 + q8;
        short8 A[4], Bv[4];
#pragma unroll
        for (int mi = 0; mi < 4; mi++)
            A[mi] = *(const short8*)(vb + (size_t)(mi * 16 + lrow) * 64 + j0);
#pragma unroll
        for (int ni = 0; ni < 4; ni++)
            Bv[ni] = *(const short8*)(ab + (size_t)(ni * 16 + lrow) * 64 + j0);
#pragma unroll
        for (int mi = 0; mi < 4; mi++)
#pragma unroll
            for (int ni = 0; ni < 4; ni++)
                acc[mi][ni] = mfma16(A[mi], Bv[ni], acc[mi][ni]);
    }
    int rq = (lane >> 4) * 4;
#pragma unroll
    for (int mi = 0; mi < 4; mi++)
#pragma unroll
        for (int r = 0; r < 4; r++) {
            int d = mi * 16 + rq + r;
            short* row = G + ((size_t)(b * 256 + c) * 64 + d) * 64;
#pragma unroll
            for (int ni = 0; ni < 4; ni++)
                row[ni * 16 + lrow] = f2bf(acc[mi][ni][r]);
        }
}

// ---------- 6. final: out[b,p,r,c] = gamma * G[b,c,r,p] + x[b,p,r,c] ----------
__global__ __launch_bounds__(256) void final_k(const short* G, const void* x,
                                               const void* gamma, void* out, const int* flagp)
{
    int f32 = *flagp;
    int t = threadIdx.x;               // = channel c
    int b = blockIdx.x >> 6, r = blockIdx.x & 63;
    const short* grow = G + ((size_t)(b * 256 + t) * 64 + r) * 64;
    float gm = f32 ? ((const float*)gamma)[0] : bf2f(((const short*)gamma)[0]);
    size_t obase = ((size_t)(b * 64) * 64 + r) * 256 + t;   // p stride 16384
    if (f32) {
        const float* xs = (const float*)x;
        float* os = (float*)out;
#pragma unroll
        for (int p8 = 0; p8 < 8; p8++) {
            short8 gv = *(const short8*)(grow + p8 * 8);
#pragma unroll
            for (int l = 0; l < 8; l++) {
                size_t off = obase + (size_t)(p8 * 8 + l) * 16384;
                os[off] = gm * bf2f(gv[l]) + xs[off];
            }
        }
    } else {
        const short* xs = (const short*)x;
        short* os = (short*)out;
#pragma unroll
        for (int p8 = 0; p8 < 8; p8++) {
            short8 gv = *(const short8*)(grow + p8 * 8);
#pragma unroll
            for (int l = 0; l < 8; l++) {
                size_t off = obase + (size_t)(p8 * 8 + l) * 16384;
                os[off] = f2bf(gm * bf2f(gv[l]) + bf2f(xs[off]));
            }
        }
    }
}

// ---------- launch ----------
extern "C" void kernel_launch(void* const* d_in, const int* in_sizes, int n_in,
                              void* d_out, int out_size, void* d_ws, size_t ws_size,
                              hipStream_t stream)
{
    const void* x   = d_in[0];
    Ptrs P{ d_in[1], d_in[3], d_in[5], d_in[7], d_in[9], d_in[11], d_in[13],
            d_in[2], d_in[4], d_in[6], d_in[8], d_in[10], d_in[12], d_in[14], d_in[15] };

    short* ws   = (short*)d_ws;
    short* qcat = ws;                     // R0: 8.4M bf16
    short* k1   = ws + 8388608;           // R1
    short* qp   = ws + 16777216;          // R2  q planar-T [b][c][w][h]
    short* kp   = ws + 25165824;          // R3  k planar   [b][c][h][w]
    short* vp   = ws + 33554432;          // R4  v planar   [b][c][h][w]
    short* wp   = ws + 41943040;          // packed weights (1,179,648)
    short* bb   = ws + 43122688;          // biases(1025) + pad + zeros(248 @ +1032)
    int*   flag = (int*)(ws + 43123968);
    short* xb   = qp;                     // x bf16; dead before qp written
    float* Et   = (float*)d_ws;           // aliases R0+R1 (dead after dispatch B)
    short* att  = qp;                     // aliases R2 (qp dead after energy)
    short* G    = kp;                     // aliases R3 (kp dead after energy)
    const short* zp = bb + 1032;          // 16-B-aligned zero block (496 B)

    detect_k<<<1, 256, 0, stream>>>((const short*)x, flag);
    convert_x<<<4096, 256, 0, stream>>>(x, xb, flag);
    convert_k<<<4613, 256, 0, stream>>>(P, wp, bb, flag);

    // A1: k-first-pass 3x3 conv (xb -> k1), fine-pipelined
    C8Job A8{ xb, k1, wp + 524288, bb + 512, 0 };
    conv8_tile<<<256, 512, 0, stream>>>(A8, zp);

    // A2: remaining x-reading convs, LONG jobs first (1024 blocks)
    CJob j1{ xb, qcat, wp + 16384,   bb + 64,  64,  1, 9, 64,  0 };
    CJob j2{ xb, qcat, wp + 163840,  bb + 128, 64,  3, 9, 128, 0 };
    CJob j3{ xb, qcat, wp + 311296,  bb + 192, 64,  6, 9, 192, 0 };
    CJob jb{ xb, vp,   wp + 1114112, bb + 768, 256, 1, 1, 0,   2 };
    CJob ja{ xb, qcat, wp + 0,       bb + 0,   64,  1, 1, 0,   0 };
    CTable TA{ { j1, j2, j3, jb, ja, ja }, { 128, 256, 384, 896, 1024, 1024 } };
    conv_tile<<<1024, 256, 0, stream>>>(TA, zp);

    // B1: k-second-pass 3x3 conv (k1 -> kp planar), fine-pipelined
    C8Job B8{ k1, kp, wp + 524288, bb + 512, 2 };
    conv8_tile<<<256, 512, 0, stream>>>(B8, zp);

    // B2: q = 1x1(qcat) -> planar-T (transposed-source addressing)
    CJob j5{ qcat, qp, wp + 458752, bb + 256, 256, 1, 1, 0, 3 };
    CTable TB{ { j5, j5, j5, j5, j5, j5 }, { 512, 512, 512, 512, 512, 512 } };
    conv_tile<<<512, 256, 0, stream>>>(TB, zp);

    energy_mfma<<<512, 256, 0, stream>>>(qp, kp, Et);
    softmax_k<<<1024, 256, 0, stream>>>(Et, att);
    out_mfma<<<512, 256, 0, stream>>>(vp, att, G);
    final_k<<<512, 256, 0, stream>>>(G, x, d_in[15], d_out, flag);
}

// Round 5
// 313.952 us; speedup vs baseline: 1.0856x; 1.0856x over previous
//
#include <hip/hip_runtime.h>

// ---------- types ----------
typedef short  short8 __attribute__((ext_vector_type(8)));
typedef short  sv4    __attribute__((ext_vector_type(4)));   // 'short4' collides with HIP typedef
typedef __bf16 bf16x8 __attribute__((ext_vector_type(8)));
typedef float  f32x4  __attribute__((ext_vector_type(4)));

__device__ __forceinline__ float bf2f(short s) {
    unsigned u = ((unsigned)(unsigned short)s) << 16;
    return __builtin_bit_cast(float, u);
}
__device__ __forceinline__ short f2bf(float f) {
    unsigned u = __builtin_bit_cast(unsigned, f);
    u += 0x7fffu + ((u >> 16) & 1u);   // RNE
    return (short)(u >> 16);
}
__device__ __forceinline__ f32x4 mfma16(short8 a, short8 b, f32x4 c) {
    return __builtin_amdgcn_mfma_f32_16x16x32_bf16(
        __builtin_bit_cast(bf16x8, a), __builtin_bit_cast(bf16x8, b), c, 0, 0, 0);
}
// async global->LDS, 16B/lane; LDS dest = wave-uniform base + lane*16
__device__ __forceinline__ void gl16(const short* g, short* l) {
    __builtin_amdgcn_global_load_lds(
        (const __attribute__((address_space(1))) void*)g,
        (__attribute__((address_space(3))) void*)l, 16, 0, 0);
}

// Geometry: B=8, H=W=64, C=256, CQ=64
// x NHWC: idx = ((b*64+h)*64+w)*256 + c ; planar [b][c][h][w]

// ---------- 0. dtype detect ----------
__global__ __launch_bounds__(256) void detect_k(const short* x, int* flag)
{
    __shared__ int red[256];
    int t = threadIdx.x;
    int cnt = 0;
    for (int i = t; i < 4096; i += 256) {
        int e = (x[2 * i] >> 7) & 0xFF;
        cnt += (e >= 100 && e <= 140) ? 1 : 0;
    }
    red[t] = cnt; __syncthreads();
    for (int s = 128; s > 0; s >>= 1) { if (t < s) red[t] += red[t + s]; __syncthreads(); }
    if (t == 0) *flag = (red[0] < 3277) ? 1 : 0;   // 1 => inputs are fp32
}

// ---------- 1a. x -> bf16 ----------
__global__ __launch_bounds__(256) void convert_x(const void* x, short* xb, const int* flagp)
{
    int f32 = *flagp;
    size_t i = ((size_t)blockIdx.x * 256 + threadIdx.x) * 8;
    short8 v;
    if (f32) {
        const float* fs = (const float*)x + i;
        f32x4 a = *(const f32x4*)fs;
        f32x4 b = *(const f32x4*)(fs + 4);
#pragma unroll
        for (int l = 0; l < 4; l++) { v[l] = f2bf(a[l]); v[4 + l] = f2bf(b[l]); }
    } else {
        v = *(const short8*)((const short*)x + i);
    }
    *(short8*)(xb + i) = v;
}

// ---------- 1b. weight repack (coalesced 64x64 LDS transpose) + biases ----------
// src layout [t][ci][co] (HWIO), dst [t][co][ci]. Old version read with stride
// Cout (4B per 64B line, ~75MB effective fetch); this reads AND writes
// coalesced via a padded LDS tile.
struct Ptrs {
    const void *wq, *wq1, *wq2, *wq3, *wq4, *wk, *wv;
    const void *bq, *bq1, *bq2, *bq3, *bq4, *bk, *bv, *gm;
};

__global__ __launch_bounds__(256) void convert_k(Ptrs P, short* wp, short* bb, const int* flagp)
{
    int f32 = *flagp;
    int bid = blockIdx.x;
    int tid = threadIdx.x;
    if (bid < 288) {
        __shared__ short T[64][66];
        const void* src; int Cout, dbase, lb;
        if      (bid <   4) { src = P.wq;  Cout =  64; dbase = 0;       lb = bid; }
        else if (bid <  40) { src = P.wq1; Cout =  64; dbase = 16384;   lb = bid - 4; }
        else if (bid <  76) { src = P.wq2; Cout =  64; dbase = 163840;  lb = bid - 40; }
        else if (bid < 112) { src = P.wq3; Cout =  64; dbase = 311296;  lb = bid - 76; }
        else if (bid < 128) { src = P.wq4; Cout = 256; dbase = 458752;  lb = bid - 112; }
        else if (bid < 272) { src = P.wk;  Cout = 256; dbase = 524288;  lb = bid - 128; }
        else                { src = P.wv;  Cout = 256; dbase = 1114112; lb = bid - 272; }
        int t, ci0, co0;
        if (Cout == 64) { t = lb >> 2; ci0 = (lb & 3) * 64; co0 = 0; }
        else            { t = lb >> 4; ci0 = ((lb >> 2) & 3) * 64; co0 = (lb & 3) * 64; }
        int rrow = tid >> 6, ccol = tid & 63;
#pragma unroll
        for (int r = 0; r < 16; ++r) {
            int cir = r * 4 + rrow;
            long si = (long)(t * 256 + ci0 + cir) * Cout + co0 + ccol;
            T[cir][ccol] = f32 ? f2bf(((const float*)src)[si]) : ((const short*)src)[si];
        }
        __syncthreads();
#pragma unroll
        for (int r = 0; r < 16; ++r) {
            int cow = r * 4 + rrow;
            wp[dbase + (t * Cout + co0 + cow) * 256 + ci0 + ccol] = T[ccol][cow];
        }
    } else {
        // biases(1025) + zero block (248 shorts @ +1032)
        for (int j = tid; j < 1280; j += 256) {
            if (j < 1025) {
                const void* src; int off;
                if      (j <   64) { src = P.bq;  off = j; }
                else if (j <  128) { src = P.bq1; off = j - 64; }
                else if (j <  192) { src = P.bq2; off = j - 128; }
                else if (j <  256) { src = P.bq3; off = j - 192; }
                else if (j <  512) { src = P.bq4; off = j - 256; }
                else if (j <  768) { src = P.bk;  off = j - 512; }
                else if (j < 1024) { src = P.bv;  off = j - 768; }
                else               { src = P.gm;  off = 0; }
                bb[j] = f32 ? f2bf(((const float*)src)[off]) : ((const short*)src)[off];
            } else if (j >= 1032) {
                bb[j] = 0;
            }
        }
    }
}

// ---------- 2. conv: block-tiled implicit GEMM, BK=64, XOR-swizzled LDS ----------
// block = 4 waves. Cout=256: 128M x 128N (2x2 waves). Cout=64: 256M x 64N (4x1).
// LDS row = 64 shorts (128B); logical chunk c (8 shorts) of row r stored at chunk c^(r&7).
struct CJob {
    const short* src;   // NHWC bf16, Cin=256
    short*       dst;
    const short* wpk;   // packed [t][co][ci]
    const short* bias;
    int Cout;           // 64 or 256
    int dil;
    int ntaps;          // 1 or 9
    int coff;           // dst channel offset (outmode 0)
    int outmode;        // 0: NHWC+coff  2: planar [b][c][h][w]
                        // 3: planar-T [b][c][w][h] via TRANSPOSED SOURCE (1x1 only)
};
struct CTable { CJob j[6]; int end[6]; };

template<int NA, int NB, int BOFS, int WSTEP>
__device__ __forceinline__ void conv_loop(
    const short* src, const short* wpk, int ntaps, int dil,
    const short* zp, short* Sh,
    int wave, int lr8, int cl, int h0, int b, int nt0, int srcT,
    int m_base, int n_base, int lrow, int pc0, int pc1,
    f32x4 (&acc)[4][4])
{
    const short* abase[NA];
    unsigned     vm[NA];
    const short* bbase[NB];
#pragma unroll
    for (int jj = 0; jj < NA; jj++) {
        int m  = (jj * 4 + wave) * 8 + lr8;
        int hh = srcT ? (m & 63) : (h0 + (m >> 6));
        int ww = srcT ? (h0 + (m >> 6)) : (m & 63);
        abase[jj] = src + (((b * 64 + hh) * 64 + ww) * 256 + cl * 8);
        unsigned msk = 1u;
        if (ntaps == 9) {
            msk = 0u;
#pragma unroll
            for (int t = 0; t < 9; ++t) {
                int tr = (t >= 6) ? 2 : ((t >= 3) ? 1 : 0);
                int dy = (tr - 1) * dil, dx = (t - tr * 3 - 1) * dil;
                bool v = ((unsigned)(hh + dy) < 64u) && ((unsigned)(ww + dx) < 64u);
                msk |= (v ? 1u : 0u) << t;
            }
        }
        vm[jj] = msk;
    }
#pragma unroll
    for (int jj = 0; jj < NB; jj++) {
        int n = (jj * 4 + wave) * 8 + lr8;
        bbase[jj] = wpk + (nt0 + n) * 256 + cl * 8;
    }

    int prevdel = 0;
    for (int t = 0; t < ntaps; ++t) {
        int dy = 0, dx = 0;
        if (ntaps == 9) {
            int tr = (t >= 6) ? 2 : ((t >= 3) ? 1 : 0);
            dy = (tr - 1) * dil;
            dx = (t - tr * 3 - 1) * dil;
        }
        int tdel = (dy * 64 + dx) * 256;
        int step = tdel - prevdel; prevdel = tdel;
        const short* pA[NA];
#pragma unroll
        for (int jj = 0; jj < NA; jj++) {
            abase[jj] += step;
            pA[jj] = ((vm[jj] >> t) & 1u) ? abase[jj] : zp;
        }
#pragma unroll
        for (int s4 = 0; s4 < 4; ++s4) {
#pragma unroll
            for (int jj = 0; jj < NA; jj++)
                gl16(pA[jj] + s4 * 64, Sh + (jj * 4 + wave) * 512);
#pragma unroll
            for (int jj = 0; jj < NB; jj++)
                gl16(bbase[jj] + s4 * 64, Sh + BOFS + (jj * 4 + wave) * 512);
            __syncthreads();
#pragma unroll
            for (int j = 0; j < 2; j++) {
                int pc = j ? pc1 : pc0;
                short8 a4[4], b4[4];
#pragma unroll
                for (int mi = 0; mi < 4; mi++)
                    a4[mi] = *(const short8*)(Sh + (m_base + mi * 16 + lrow) * 64 + pc);
#pragma unroll
                for (int ni = 0; ni < 4; ni++)
                    b4[ni] = *(const short8*)(Sh + BOFS + (n_base + ni * 16 + lrow) * 64 + pc);
#pragma unroll
                for (int mi = 0; mi < 4; mi++)
#pragma unroll
                    for (int ni = 0; ni < 4; ni++)
                        acc[mi][ni] = mfma16(a4[mi], b4[ni], acc[mi][ni]);
            }
            __syncthreads();
        }
#pragma unroll
        for (int jj = 0; jj < NB; jj++) bbase[jj] += WSTEP;
    }
}

__global__ __launch_bounds__(256, 3) void conv_tile(CTable T, const short* zp)
{
    __shared__ short Sh[20480];   // 40 KB: A at 0, B at BOFS
    int tid = threadIdx.x;
    int bid = blockIdx.x;
    int ji = 0;
    while (ji < 5 && bid >= T.end[ji]) ji++;
    CJob J = T.j[ji];
    // XCD-chunked swizzle WITHIN the job segment (segment sizes %8==0, starts %8==0)
    int s0  = ji ? T.end[ji - 1] : 0;
    int seg = T.end[ji] - s0;
    int lb  = bid - s0;
    int g   = (lb & 7) * (seg >> 3) + (lb >> 3);

    int big   = (J.Cout == 256);
    int BM    = big ? 128 : 256;
    int ntile = big ? (g & 1) : 0;
    int Mtile = big ? (g >> 1) : g;
    int p0 = Mtile * BM;
    int b  = p0 >> 12;
    int h0 = (p0 >> 6) & 63;      // outmode 3: this is w0 (positions are h-inner)
    int nt0  = ntile * 128;
    int srcT = (J.outmode == 3);

    int wave = tid >> 6, lane = tid & 63;
    int lrow = lane & 15, quad = lane >> 4;
    int m_base = big ? (wave & 1) * 64 : wave * 64;
    int n_base = big ? (wave >> 1) * 64 : 0;

    int lr8 = lane >> 3;
    int cl  = (lane & 7) ^ (lr8 & 7);

    int pc0 = ((quad     ^ (lrow & 7)) * 8);
    int pc1 = (((4 + quad) ^ (lrow & 7)) * 8);

    f32x4 acc[4][4] = {};
    if (big)
        conv_loop<4, 4, 8192, 65536>(J.src, J.wpk, J.ntaps, J.dil, zp, Sh,
                                     wave, lr8, cl, h0, b, nt0, srcT,
                                     m_base, n_base, lrow, pc0, pc1, acc);
    else
        conv_loop<8, 2, 16384, 16384>(J.src, J.wpk, J.ntaps, J.dil, zp, Sh,
                                      wave, lr8, cl, h0, b, nt0, srcT,
                                      m_base, n_base, lrow, pc0, pc1, acc);

    int rq = quad * 4;
#pragma unroll
    for (int ni = 0; ni < 4; ni++) {
        int co = nt0 + n_base + ni * 16 + lrow;
        float bv = bf2f(J.bias[co]);
        if (J.outmode == 0) {
#pragma unroll
            for (int mi = 0; mi < 4; mi++) {
                int pb = p0 + m_base + mi * 16 + rq;
#pragma unroll
                for (int r = 0; r < 4; r++)
                    J.dst[(size_t)(pb + r) * 256 + J.coff + co] = f2bf(acc[mi][ni][r] + bv);
            }
        } else {
            int hw = h0 + (m_base >> 6);
            short* row = J.dst + ((size_t)(b * 256 + co) * 64 + hw) * 64;
#pragma unroll
            for (int mi = 0; mi < 4; mi++) {
                sv4 o;
#pragma unroll
                for (int r = 0; r < 4; r++) o[r] = f2bf(acc[mi][ni][r] + bv);
                *(sv4*)(row + mi * 16 + rq) = o;
            }
        }
    }
}

// ---------- 3. energy: Et[b,c,w,i] = sum_j kp[b,c,i,j] * qp[b,c,w,j] ----------
__global__ __launch_bounds__(256) void energy_mfma(const short* qp, const short* kp, float* Et)
{
    int wid  = threadIdx.x >> 6;
    int lane = threadIdx.x & 63;
    int g = blockIdx.x * 4 + wid;           // 0..2047
    int b = g >> 8, c = g & 255;
    int lrow = lane & 15;
    int q8   = (lane >> 4) << 3;
    const short* qb = qp + (size_t)(b * 256 + c) * 4096;
    const short* kb = kp + (size_t)(b * 256 + c) * 4096;

    f32x4 acc[4][4] = {};
#pragma unroll
    for (int ks = 0; ks < 2; ++ks) {
        int j0 = ks * 32 + q8;
        short8 A[4], Bv[4];
#pragma unroll
        for (int mi = 0; mi < 4; mi++)
            A[mi] = *(const short8*)(qb + (size_t)(mi * 16 + lrow) * 64 + j0);
#pragma unroll
        for (int ni = 0; ni < 4; ni++)
            Bv[ni] = *(const short8*)(kb + (size_t)(ni * 16 + lrow) * 64 + j0);
#pragma unroll
        for (int mi = 0; mi < 4; mi++)
#pragma unroll
            for (int ni = 0; ni < 4; ni++)
                acc[mi][ni] = mfma16(A[mi], Bv[ni], acc[mi][ni]);
    }
    int rq = (lane >> 4) * 4;
#pragma unroll
    for (int mi = 0; mi < 4; mi++)
#pragma unroll
        for (int r = 0; r < 4; r++) {
            int w = mi * 16 + rq + r;
            float* row = Et + ((size_t)(b * 256 + c) * 64 + w) * 64;
#pragma unroll
            for (int ni = 0; ni < 4; ni++)
                row[ni * 16 + lrow] = acc[mi][ni][r];
        }
}

// ---------- 4. softmax over c ----------
__global__ __launch_bounds__(256) void softmax_k(const float* Et, short* att)
{
    __shared__ float S[256 * 33];
    __shared__ float red[256];
    __shared__ float sm[256];
    int t  = threadIdx.x;
    int b  = blockIdx.x >> 7;
    int a  = (blockIdx.x >> 1) & 63;
    int jh = blockIdx.x & 1;

    const float* row = Et + ((size_t)(b * 256 + t) * 64 + a) * 64 + jh * 32;
#pragma unroll
    for (int jj = 0; jj < 32; jj += 4) {
        f32x4 v = *(const f32x4*)(row + jj);
#pragma unroll
        for (int l = 0; l < 4; l++) S[t * 33 + jj + l] = v[l];
    }
    __syncthreads();

    int tj = t & 31, tg = t >> 5;
    float m = -1e30f;
#pragma unroll
    for (int cc = 0; cc < 32; ++cc) m = fmaxf(m, S[(tg * 32 + cc) * 33 + tj]);
    red[t] = m;
    __syncthreads();
    if (tg == 0) {
        float mm = red[tj];
#pragma unroll
        for (int gg = 1; gg < 8; ++gg) mm = fmaxf(mm, red[gg * 32 + tj]);
        red[tj] = mm;
    }
    __syncthreads();
    float M = red[tj];
    float s = 0.f;
#pragma unroll
    for (int cc = 0; cc < 32; ++cc) {
        int id = (tg * 32 + cc) * 33 + tj;
        float e = __expf(S[id] - M);
        S[id] = e; s += e;
    }
    sm[t] = s;
    __syncthreads();
    if (tg == 0) {
        float ss = sm[tj];
#pragma unroll
        for (int gg = 1; gg < 8; ++gg) ss += sm[gg * 32 + tj];
        sm[tj] = 1.0f / ss;
    }
    __syncthreads();

    short* orow = att + ((size_t)(b * 256 + t) * 64 + a) * 64 + jh * 32;
#pragma unroll
    for (int jj = 0; jj < 32; jj += 8) {
        short8 o;
#pragma unroll
        for (int l = 0; l < 8; l++) o[l] = f2bf(S[t * 33 + jj + l] * sm[jj + l]);
        *(short8*)(orow + jj) = o;
    }
}

// ---------- 5. fused out+final: out[b,p,r,c] = gamma*PV[b,c,r,p] + x[b,p,r,c] ----
// Block = (b, 8 consecutive c), 8 waves, one 64x64x64 PV matmul per wave.
// Epilogue: per 16-row d-chunk, transpose via padded LDS and write
// out[b][p][d][c0..c0+7] (32B f32 / 16B bf16 chunks). Block->XCD mapping
// b = bid&7 puts BOTH c-halves of a 64B line (and all of batch b's
// vp/att/x traffic) on one XCD's L2, so partial sectors merge before
// eviction. Eliminates the G materialization (67 MB round-trip) and G's
// intermediate bf16 rounding.
__global__ __launch_bounds__(512) void out_final(const short* vp, const short* att,
                                                 const void* x, const void* gamma,
                                                 void* out, const int* flagp)
{
    __shared__ float S[8 * 16 * 66];   // [c'][d'][a], a padded to 66
    int f32 = *flagp;
    int tid = threadIdx.x;
    int wid = tid >> 6, lane = tid & 63;
    int b  = blockIdx.x & 7;                 // batch per XCD
    int c0 = (blockIdx.x >> 3) * 8;          // 32 c-groups per batch
    int c  = c0 + wid;
    int lrow = lane & 15, quad = lane >> 4;
    int q8 = quad << 3;
    const short* vb = vp  + (size_t)(b * 256 + c) * 4096;
    const short* ab = att + (size_t)(b * 256 + c) * 4096;

    f32x4 acc[4][4] = {};
#pragma unroll
    for (int ks = 0; ks < 2; ++ks) {
        int j0 = ks * 32 + q8;
        short8 A[4], Bv[4];
#pragma unroll
        for (int mi = 0; mi < 4; mi++)
            A[mi] = *(const short8*)(vb + (size_t)(mi * 16 + lrow) * 64 + j0);
#pragma unroll
        for (int ni = 0; ni < 4; ni++)
            Bv[ni] = *(const short8*)(ab + (size_t)(ni * 16 + lrow) * 64 + j0);
#pragma unroll
        for (int mi = 0; mi < 4; mi++)
#pragma unroll
            for (int ni = 0; ni < 4; ni++)
                acc[mi][ni] = mfma16(A[mi], Bv[ni], acc[mi][ni]);
    }

    float gm = f32 ? ((const float*)gamma)[0] : bf2f(((const short*)gamma)[0]);
    int rq = quad * 4;
#pragma unroll
    for (int mi = 0; mi < 4; mi++) {
        // stage this wave's d-chunk: S[c'=wid][d'=rq+r][a=ni*16+lrow]
#pragma unroll
        for (int ni = 0; ni < 4; ni++)
#pragma unroll
            for (int r = 0; r < 4; r++)
                S[(wid * 16 + rq + r) * 66 + ni * 16 + lrow] = acc[mi][ni][r];
        __syncthreads();
#pragma unroll
        for (int it = 0; it < 2; ++it) {
            int idx = it * 512 + tid;        // covers [16 d'][64 p]
            int dp = idx >> 6;
            int p  = idx & 63;
            int dg = mi * 16 + dp;
            size_t off = ((size_t)((b * 64 + p) * 64 + dg)) * 256 + c0;
            if (f32) {
                const float* xs = (const float*)x + off;
                float* os = (float*)out + off;
                f32x4 xv0 = *(const f32x4*)xs;
                f32x4 xv1 = *(const f32x4*)(xs + 4);
                f32x4 o0, o1;
#pragma unroll
                for (int l = 0; l < 4; l++) {
                    o0[l] = gm * S[((l    ) * 16 + dp) * 66 + p] + xv0[l];
                    o1[l] = gm * S[((l + 4) * 16 + dp) * 66 + p] + xv1[l];
                }
                *(f32x4*)os = o0;
                *(f32x4*)(os + 4) = o1;
            } else {
                const short* xs = (const short*)x + off;
                short* os = (short*)out + off;
                short8 xv = *(const short8*)xs, o;
#pragma unroll
                for (int l = 0; l < 8; l++)
                    o[l] = f2bf(gm * S[(l * 16 + dp) * 66 + p] + bf2f(xv[l]));
                *(short8*)os = o;
            }
        }
        __syncthreads();
    }
}

// ---------- launch ----------
extern "C" void kernel_launch(void* const* d_in, const int* in_sizes, int n_in,
                              void* d_out, int out_size, void* d_ws, size_t ws_size,
                              hipStream_t stream)
{
    const void* x   = d_in[0];
    Ptrs P{ d_in[1], d_in[3], d_in[5], d_in[7], d_in[9], d_in[11], d_in[13],
            d_in[2], d_in[4], d_in[6], d_in[8], d_in[10], d_in[12], d_in[14], d_in[15] };

    short* ws   = (short*)d_ws;
    short* qcat = ws;                     // R0: 8.4M bf16
    short* k1   = ws + 8388608;           // R1
    short* qp   = ws + 16777216;          // R2  q planar-T [b][c][w][h]
    short* kp   = ws + 25165824;          // R3  k planar   [b][c][h][w]
    short* vp   = ws + 33554432;          // R4  v planar   [b][c][h][w]
    short* wp   = ws + 41943040;          // packed weights (1,179,648)
    short* bb   = ws + 43122688;          // biases(1025) + pad + zeros(248 @ +1032)
    int*   flag = (int*)(ws + 43123968);
    short* xb   = qp;                     // x bf16; dead before qp written
    float* Et   = (float*)d_ws;           // aliases R0+R1 (dead after dispatch B)
    short* att  = qp;                     // aliases R2 (qp dead after energy)
    const short* zp = bb + 1032;          // 16-B-aligned zero block (496 B)

    detect_k<<<1, 256, 0, stream>>>((const short*)x, flag);
    convert_x<<<4096, 256, 0, stream>>>(x, xb, flag);
    convert_k<<<289, 256, 0, stream>>>(P, wp, bb, flag);

    // dispatch A: six x-reading convs, LONG jobs first (1536 blocks)
    // segment sizes 512,128,128,128,512,128 — all %8==0 for the XCD swizzle
    CJob j4{ xb, k1,   wp + 524288,  bb + 512, 256, 1, 9, 0,   0 };
    CJob j1{ xb, qcat, wp + 16384,   bb + 64,  64,  1, 9, 64,  0 };
    CJob j2{ xb, qcat, wp + 163840,  bb + 128, 64,  3, 9, 128, 0 };
    CJob j3{ xb, qcat, wp + 311296,  bb + 192, 64,  6, 9, 192, 0 };
    CJob jb{ xb, vp,   wp + 1114112, bb + 768, 256, 1, 1, 0,   2 };
    CJob ja{ xb, qcat, wp + 0,       bb + 0,   64,  1, 1, 0,   0 };
    CTable TA{ { j4, j1, j2, j3, jb, ja }, { 512, 640, 768, 896, 1408, 1536 } };
    conv_tile<<<1536, 256, 0, stream>>>(TA, zp);

    // dispatch B: k = 3x3(k1) -> planar, then q = 1x1(qcat) -> planar-T
    CJob j6{ k1,   kp, wp + 524288, bb + 512, 256, 1, 9, 0, 2 };
    CJob j5{ qcat, qp, wp + 458752, bb + 256, 256, 1, 1, 0, 3 };
    CTable TB{ { j6, j5, j5, j5, j5, j5 }, { 512, 1024, 1024, 1024, 1024, 1024 } };
    conv_tile<<<1024, 256, 0, stream>>>(TB, zp);

    energy_mfma<<<512, 256, 0, stream>>>(qp, kp, Et);
    softmax_k<<<1024, 256, 0, stream>>>(Et, att);
    out_final<<<256, 512, 0, stream>>>(vp, att, x, d_in[15], d_out, flag);
}

// Round 6
// 304.131 us; speedup vs baseline: 1.1207x; 1.0323x over previous
//
#include <hip/hip_runtime.h>

// ---------- types ----------
typedef short  short8 __attribute__((ext_vector_type(8)));
typedef short  sv4    __attribute__((ext_vector_type(4)));   // 'short4' collides with HIP typedef
typedef __bf16 bf16x8 __attribute__((ext_vector_type(8)));
typedef float  f32x4  __attribute__((ext_vector_type(4)));

__device__ __forceinline__ float bf2f(short s) {
    unsigned u = ((unsigned)(unsigned short)s) << 16;
    return __builtin_bit_cast(float, u);
}
__device__ __forceinline__ short f2bf(float f) {
    unsigned u = __builtin_bit_cast(unsigned, f);
    u += 0x7fffu + ((u >> 16) & 1u);   // RNE
    return (short)(u >> 16);
}
__device__ __forceinline__ f32x4 mfma16(short8 a, short8 b, f32x4 c) {
    return __builtin_amdgcn_mfma_f32_16x16x32_bf16(
        __builtin_bit_cast(bf16x8, a), __builtin_bit_cast(bf16x8, b), c, 0, 0, 0);
}
// async global->LDS, 16B/lane; LDS dest = wave-uniform base + lane*16
__device__ __forceinline__ void gl16(const short* g, short* l) {
    __builtin_amdgcn_global_load_lds(
        (const __attribute__((address_space(1))) void*)g,
        (__attribute__((address_space(3))) void*)l, 16, 0, 0);
}

// Geometry: B=8, H=W=64, C=256, CQ=64
// x NHWC: idx = ((b*64+h)*64+w)*256 + c ; planar [b][c][h][w]

// ---------- 0. dtype detect ----------
__global__ __launch_bounds__(256) void detect_k(const short* x, int* flag)
{
    __shared__ int red[256];
    int t = threadIdx.x;
    int cnt = 0;
    for (int i = t; i < 4096; i += 256) {
        int e = (x[2 * i] >> 7) & 0xFF;
        cnt += (e >= 100 && e <= 140) ? 1 : 0;
    }
    red[t] = cnt; __syncthreads();
    for (int s = 128; s > 0; s >>= 1) { if (t < s) red[t] += red[t + s]; __syncthreads(); }
    if (t == 0) *flag = (red[0] < 3277) ? 1 : 0;   // 1 => inputs are fp32
}

// ---------- 1a. x -> bf16 ----------
__global__ __launch_bounds__(256) void convert_x(const void* x, short* xb, const int* flagp)
{
    int f32 = *flagp;
    size_t i = ((size_t)blockIdx.x * 256 + threadIdx.x) * 8;
    short8 v;
    if (f32) {
        const float* fs = (const float*)x + i;
        f32x4 a = *(const f32x4*)fs;
        f32x4 b = *(const f32x4*)(fs + 4);
#pragma unroll
        for (int l = 0; l < 4; l++) { v[l] = f2bf(a[l]); v[4 + l] = f2bf(b[l]); }
    } else {
        v = *(const short8*)((const short*)x + i);
    }
    *(short8*)(xb + i) = v;
}

// ---------- 1b. weight repack (coalesced 64x64 LDS transpose) + biases ----------
struct Ptrs {
    const void *wq, *wq1, *wq2, *wq3, *wq4, *wk, *wv;
    const void *bq, *bq1, *bq2, *bq3, *bq4, *bk, *bv, *gm;
};

__global__ __launch_bounds__(256) void convert_k(Ptrs P, short* wp, short* bb, const int* flagp)
{
    int f32 = *flagp;
    int bid = blockIdx.x;
    int tid = threadIdx.x;
    if (bid < 288) {
        __shared__ short T[64][66];
        const void* src; int Cout, dbase, lb;
        if      (bid <   4) { src = P.wq;  Cout =  64; dbase = 0;       lb = bid; }
        else if (bid <  40) { src = P.wq1; Cout =  64; dbase = 16384;   lb = bid - 4; }
        else if (bid <  76) { src = P.wq2; Cout =  64; dbase = 163840;  lb = bid - 40; }
        else if (bid < 112) { src = P.wq3; Cout =  64; dbase = 311296;  lb = bid - 76; }
        else if (bid < 128) { src = P.wq4; Cout = 256; dbase = 458752;  lb = bid - 112; }
        else if (bid < 272) { src = P.wk;  Cout = 256; dbase = 524288;  lb = bid - 128; }
        else                { src = P.wv;  Cout = 256; dbase = 1114112; lb = bid - 272; }
        int t, ci0, co0;
        if (Cout == 64) { t = lb >> 2; ci0 = (lb & 3) * 64; co0 = 0; }
        else            { t = lb >> 4; ci0 = ((lb >> 2) & 3) * 64; co0 = (lb & 3) * 64; }
        int rrow = tid >> 6, ccol = tid & 63;
#pragma unroll
        for (int r = 0; r < 16; ++r) {
            int cir = r * 4 + rrow;
            long si = (long)(t * 256 + ci0 + cir) * Cout + co0 + ccol;
            T[cir][ccol] = f32 ? f2bf(((const float*)src)[si]) : ((const short*)src)[si];
        }
        __syncthreads();
#pragma unroll
        for (int r = 0; r < 16; ++r) {
            int cow = r * 4 + rrow;
            wp[dbase + (t * Cout + co0 + cow) * 256 + ci0 + ccol] = T[ccol][cow];
        }
    } else {
        for (int j = tid; j < 1280; j += 256) {
            if (j < 1025) {
                const void* src; int off;
                if      (j <   64) { src = P.bq;  off = j; }
                else if (j <  128) { src = P.bq1; off = j - 64; }
                else if (j <  192) { src = P.bq2; off = j - 128; }
                else if (j <  256) { src = P.bq3; off = j - 192; }
                else if (j <  512) { src = P.bq4; off = j - 256; }
                else if (j <  768) { src = P.bk;  off = j - 512; }
                else if (j < 1024) { src = P.bv;  off = j - 768; }
                else               { src = P.gm;  off = 0; }
                bb[j] = f32 ? f2bf(((const float*)src)[off]) : ((const short*)src)[off];
            } else if (j >= 1032) {
                bb[j] = 0;                 // zero block for OOB staging
            }
        }
    }
}

// ---------- 2. conv_med: occupancy-oriented implicit GEMM ----------
// 4 waves/block, per-wave output 32x64 (acc[2][4] -> 32 AGPRs), 24 KB LDS.
// big (Cout=256): BM=64 x BN=128 -> 1024 blocks/job (4-6 resident/CU).
// small (Cout=64): BM=128 x BN=64 -> 256 blocks/job.
// LDS row = 64 shorts; chunk c of row r stored at chunk c^(r&7) (pre-swizzled
// global source, linear gl16 dest).
struct CJob {
    const short* src;   // NHWC bf16, Cin=256
    short*       dst;
    const short* wpk;   // packed [t][co][ci]
    const short* bias;
    int Cout;           // 64 or 256
    int dil;
    int ntaps;          // 1 or 9
    int coff;           // dst channel offset (outmode 0)
    int outmode;        // 0: NHWC+coff  2: planar [b][c][h][w]
                        // 3: planar-T [b][c][w][h] via TRANSPOSED SOURCE (1x1 only)
};
struct CTable { CJob j[6]; int end[6]; };

template<int NA, int NB, int BOFS, int WSTEP>
__device__ __forceinline__ void conv_med_loop(
    const short* src, const short* wpk, int ntaps, int dil,
    const short* zp, short* Sh,
    int wave, int lr8, int cl, int h0, int b, int nt0, int srcT,
    int m_base, int n_base, int lrow, int pc0, int pc1,
    f32x4 (&acc)[2][4])
{
    const short* abase[NA];
    unsigned     vm[NA];
    const short* bbase[NB];
#pragma unroll
    for (int jj = 0; jj < NA; jj++) {
        int m  = (jj * 4 + wave) * 8 + lr8;
        int hh = srcT ? (m & 63) : (h0 + (m >> 6));
        int ww = srcT ? (h0 + (m >> 6)) : (m & 63);
        abase[jj] = src + (((b * 64 + hh) * 64 + ww) * 256 + cl * 8);
        unsigned msk = 1u;
        if (ntaps == 9) {
            msk = 0u;
#pragma unroll
            for (int t = 0; t < 9; ++t) {
                int tr = (t >= 6) ? 2 : ((t >= 3) ? 1 : 0);
                int dy = (tr - 1) * dil, dx = (t - tr * 3 - 1) * dil;
                bool v = ((unsigned)(hh + dy) < 64u) && ((unsigned)(ww + dx) < 64u);
                msk |= (v ? 1u : 0u) << t;
            }
        }
        vm[jj] = msk;
    }
#pragma unroll
    for (int jj = 0; jj < NB; jj++) {
        int n = (jj * 4 + wave) * 8 + lr8;
        bbase[jj] = wpk + (nt0 + n) * 256 + cl * 8;
    }

    int prevdel = 0;
    for (int t = 0; t < ntaps; ++t) {
        int dy = 0, dx = 0;
        if (ntaps == 9) {
            int tr = (t >= 6) ? 2 : ((t >= 3) ? 1 : 0);
            dy = (tr - 1) * dil;
            dx = (t - tr * 3 - 1) * dil;
        }
        int tdel = (dy * 64 + dx) * 256;
        int step = tdel - prevdel; prevdel = tdel;
        const short* pA[NA];
#pragma unroll
        for (int jj = 0; jj < NA; jj++) {
            abase[jj] += step;
            pA[jj] = ((vm[jj] >> t) & 1u) ? abase[jj] : zp;
        }
#pragma unroll
        for (int s4 = 0; s4 < 4; ++s4) {
#pragma unroll
            for (int jj = 0; jj < NA; jj++)
                gl16(pA[jj] + s4 * 64, Sh + (jj * 4 + wave) * 512);
#pragma unroll
            for (int jj = 0; jj < NB; jj++)
                gl16(bbase[jj] + s4 * 64, Sh + BOFS + (jj * 4 + wave) * 512);
            __syncthreads();
#pragma unroll
            for (int j = 0; j < 2; j++) {
                int pc = j ? pc1 : pc0;
                short8 a4[2], b4[4];
#pragma unroll
                for (int mi = 0; mi < 2; mi++)
                    a4[mi] = *(const short8*)(Sh + (m_base + mi * 16 + lrow) * 64 + pc);
#pragma unroll
                for (int ni = 0; ni < 4; ni++)
                    b4[ni] = *(const short8*)(Sh + BOFS + (n_base + ni * 16 + lrow) * 64 + pc);
#pragma unroll
                for (int mi = 0; mi < 2; mi++)
#pragma unroll
                    for (int ni = 0; ni < 4; ni++)
                        acc[mi][ni] = mfma16(a4[mi], b4[ni], acc[mi][ni]);
            }
            __syncthreads();
        }
#pragma unroll
        for (int jj = 0; jj < NB; jj++) bbase[jj] += WSTEP;
    }
}

__global__ __launch_bounds__(256, 4) void conv_med(CTable T, const short* zp)
{
    __shared__ short Sh[12288];   // 24 KB (big: A 4096 + B 8192; small: A 8192 + B 4096)
    int tid = threadIdx.x;
    int bid = blockIdx.x;
    int ji = 0;
    while (ji < 5 && bid >= T.end[ji]) ji++;
    CJob J = T.j[ji];
    // XCD-chunked swizzle within the job segment (sizes/starts %8==0)
    int s0  = ji ? T.end[ji - 1] : 0;
    int seg = T.end[ji] - s0;
    int lb  = bid - s0;
    int g   = (lb & 7) * (seg >> 3) + (lb >> 3);

    int big   = (J.Cout == 256);
    int BM    = big ? 64 : 128;
    int ntile = big ? (g & 1) : 0;
    int Mtile = big ? (g >> 1) : g;
    int p0 = Mtile * BM;
    int b  = p0 >> 12;
    int h0 = (p0 >> 6) & 63;      // outmode 3: this is w0 (positions are h-inner)
    int nt0  = ntile * 128;
    int srcT = (J.outmode == 3);

    int wave = tid >> 6, lane = tid & 63;
    int lrow = lane & 15, quad = lane >> 4;
    int m_base = big ? (wave & 1) * 32 : wave * 32;
    int n_base = big ? (wave >> 1) * 64 : 0;

    int lr8 = lane >> 3;
    int cl  = (lane & 7) ^ (lr8 & 7);

    int pc0 = ((quad     ^ (lrow & 7)) * 8);
    int pc1 = (((4 + quad) ^ (lrow & 7)) * 8);

    f32x4 acc[2][4] = {};
    if (big)
        conv_med_loop<2, 4, 4096, 65536>(J.src, J.wpk, J.ntaps, J.dil, zp, Sh,
                                         wave, lr8, cl, h0, b, nt0, srcT,
                                         m_base, n_base, lrow, pc0, pc1, acc);
    else
        conv_med_loop<4, 2, 8192, 16384>(J.src, J.wpk, J.ntaps, J.dil, zp, Sh,
                                         wave, lr8, cl, h0, b, nt0, srcT,
                                         m_base, n_base, lrow, pc0, pc1, acc);

    int rq = quad * 4;
#pragma unroll
    for (int ni = 0; ni < 4; ni++) {
        int co = nt0 + n_base + ni * 16 + lrow;
        float bv = bf2f(J.bias[co]);
        if (J.outmode == 0) {
#pragma unroll
            for (int mi = 0; mi < 2; mi++) {
                int pb = p0 + m_base + mi * 16 + rq;
#pragma unroll
                for (int r = 0; r < 4; r++)
                    J.dst[(size_t)(pb + r) * 256 + J.coff + co] = f2bf(acc[mi][ni][r] + bv);
            }
        } else {
            // modes 2/3: big only (BM=64 -> one planar row at h0); contiguous
            // sv4 stores along the inner axis.
            short* row = J.dst + ((size_t)(b * 256 + co) * 64 + h0) * 64;
#pragma unroll
            for (int mi = 0; mi < 2; mi++) {
                sv4 o;
#pragma unroll
                for (int r = 0; r < 4; r++) o[r] = f2bf(acc[mi][ni][r] + bv);
                *(sv4*)(row + m_base + mi * 16 + rq) = o;
            }
        }
    }
}

// ---------- 3. energy: Et[b,c,w,i] = sum_j kp[b,c,i,j] * qp[b,c,w,j] ----------
__global__ __launch_bounds__(256) void energy_mfma(const short* qp, const short* kp, float* Et)
{
    int wid  = threadIdx.x >> 6;
    int lane = threadIdx.x & 63;
    int g = blockIdx.x * 4 + wid;           // 0..2047
    int b = g >> 8, c = g & 255;
    int lrow = lane & 15;
    int q8   = (lane >> 4) << 3;
    const short* qb = qp + (size_t)(b * 256 + c) * 4096;
    const short* kb = kp + (size_t)(b * 256 + c) * 4096;

    f32x4 acc[4][4] = {};
#pragma unroll
    for (int ks = 0; ks < 2; ++ks) {
        int j0 = ks * 32 + q8;
        short8 A[4], Bv[4];
#pragma unroll
        for (int mi = 0; mi < 4; mi++)
            A[mi] = *(const short8*)(qb + (size_t)(mi * 16 + lrow) * 64 + j0);
#pragma unroll
        for (int ni = 0; ni < 4; ni++)
            Bv[ni] = *(const short8*)(kb + (size_t)(ni * 16 + lrow) * 64 + j0);
#pragma unroll
        for (int mi = 0; mi < 4; mi++)
#pragma unroll
            for (int ni = 0; ni < 4; ni++)
                acc[mi][ni] = mfma16(A[mi], Bv[ni], acc[mi][ni]);
    }
    int rq = (lane >> 4) * 4;
#pragma unroll
    for (int mi = 0; mi < 4; mi++)
#pragma unroll
        for (int r = 0; r < 4; r++) {
            int w = mi * 16 + rq + r;
            float* row = Et + ((size_t)(b * 256 + c) * 64 + w) * 64;
#pragma unroll
            for (int ni = 0; ni < 4; ni++)
                row[ni * 16 + lrow] = acc[mi][ni][r];
        }
}

// ---------- 4. softmax over c ----------
__global__ __launch_bounds__(256) void softmax_k(const float* Et, short* att)
{
    __shared__ float S[256 * 33];
    __shared__ float red[256];
    __shared__ float sm[256];
    int t  = threadIdx.x;
    int b  = blockIdx.x >> 7;
    int a  = (blockIdx.x >> 1) & 63;
    int jh = blockIdx.x & 1;

    const float* row = Et + ((size_t)(b * 256 + t) * 64 + a) * 64 + jh * 32;
#pragma unroll
    for (int jj = 0; jj < 32; jj += 4) {
        f32x4 v = *(const f32x4*)(row + jj);
#pragma unroll
        for (int l = 0; l < 4; l++) S[t * 33 + jj + l] = v[l];
    }
    __syncthreads();

    int tj = t & 31, tg = t >> 5;
    float m = -1e30f;
#pragma unroll
    for (int cc = 0; cc < 32; ++cc) m = fmaxf(m, S[(tg * 32 + cc) * 33 + tj]);
    red[t] = m;
    __syncthreads();
    if (tg == 0) {
        float mm = red[tj];
#pragma unroll
        for (int gg = 1; gg < 8; ++gg) mm = fmaxf(mm, red[gg * 32 + tj]);
        red[tj] = mm;
    }
    __syncthreads();
    float M = red[tj];
    float s = 0.f;
#pragma unroll
    for (int cc = 0; cc < 32; ++cc) {
        int id = (tg * 32 + cc) * 33 + tj;
        float e = __expf(S[id] - M);
        S[id] = e; s += e;
    }
    sm[t] = s;
    __syncthreads();
    if (tg == 0) {
        float ss = sm[tj];
#pragma unroll
        for (int gg = 1; gg < 8; ++gg) ss += sm[gg * 32 + tj];
        sm[tj] = 1.0f / ss;
    }
    __syncthreads();

    short* orow = att + ((size_t)(b * 256 + t) * 64 + a) * 64 + jh * 32;
#pragma unroll
    for (int jj = 0; jj < 32; jj += 8) {
        short8 o;
#pragma unroll
        for (int l = 0; l < 8; l++) o[l] = f2bf(S[t * 33 + jj + l] * sm[jj + l]);
        *(short8*)(orow + jj) = o;
    }
}

// ---------- 5. fused out+final: out[b,p,r,c] = gamma*PV[b,c,r,p] + x[b,p,r,c] ----
__global__ __launch_bounds__(512) void out_final(const short* vp, const short* att,
                                                 const void* x, const void* gamma,
                                                 void* out, const int* flagp)
{
    __shared__ float S[8 * 16 * 66];   // [c'][d'][a], a padded to 66
    int f32 = *flagp;
    int tid = threadIdx.x;
    int wid = tid >> 6, lane = tid & 63;
    int b  = blockIdx.x & 7;                 // batch per XCD
    int c0 = (blockIdx.x >> 3) * 8;          // 32 c-groups per batch
    int c  = c0 + wid;
    int lrow = lane & 15, quad = lane >> 4;
    int q8 = quad << 3;
    const short* vb = vp  + (size_t)(b * 256 + c) * 4096;
    const short* ab = att + (size_t)(b * 256 + c) * 4096;

    f32x4 acc[4][4] = {};
#pragma unroll
    for (int ks = 0; ks < 2; ++ks) {
        int j0 = ks * 32 + q8;
        short8 A[4], Bv[4];
#pragma unroll
        for (int mi = 0; mi < 4; mi++)
            A[mi] = *(const short8*)(vb + (size_t)(mi * 16 + lrow) * 64 + j0);
#pragma unroll
        for (int ni = 0; ni < 4; ni++)
            Bv[ni] = *(const short8*)(ab + (size_t)(ni * 16 + lrow) * 64 + j0);
#pragma unroll
        for (int mi = 0; mi < 4; mi++)
#pragma unroll
            for (int ni = 0; ni < 4; ni++)
                acc[mi][ni] = mfma16(A[mi], Bv[ni], acc[mi][ni]);
    }

    float gm = f32 ? ((const float*)gamma)[0] : bf2f(((const short*)gamma)[0]);
    int rq = quad * 4;
#pragma unroll
    for (int mi = 0; mi < 4; mi++) {
#pragma unroll
        for (int ni = 0; ni < 4; ni++)
#pragma unroll
            for (int r = 0; r < 4; r++)
                S[(wid * 16 + rq + r) * 66 + ni * 16 + lrow] = acc[mi][ni][r];
        __syncthreads();
#pragma unroll
        for (int it = 0; it < 2; ++it) {
            int idx = it * 512 + tid;        // covers [16 d'][64 p]
            int dp = idx >> 6;
            int p  = idx & 63;
            int dg = mi * 16 + dp;
            size_t off = ((size_t)((b * 64 + p) * 64 + dg)) * 256 + c0;
            if (f32) {
                const float* xs = (const float*)x + off;
                float* os = (float*)out + off;
                f32x4 xv0 = *(const f32x4*)xs;
                f32x4 xv1 = *(const f32x4*)(xs + 4);
                f32x4 o0, o1;
#pragma unroll
                for (int l = 0; l < 4; l++) {
                    o0[l] = gm * S[((l    ) * 16 + dp) * 66 + p] + xv0[l];
                    o1[l] = gm * S[((l + 4) * 16 + dp) * 66 + p] + xv1[l];
                }
                *(f32x4*)os = o0;
                *(f32x4*)(os + 4) = o1;
            } else {
                const short* xs = (const short*)x + off;
                short* os = (short*)out + off;
                short8 xv = *(const short8*)xs, o;
#pragma unroll
                for (int l = 0; l < 8; l++)
                    o[l] = f2bf(gm * S[(l * 16 + dp) * 66 + p] + bf2f(xv[l]));
                *(short8*)os = o;
            }
        }
        __syncthreads();
    }
}

// ---------- launch ----------
extern "C" void kernel_launch(void* const* d_in, const int* in_sizes, int n_in,
                              void* d_out, int out_size, void* d_ws, size_t ws_size,
                              hipStream_t stream)
{
    const void* x   = d_in[0];
    Ptrs P{ d_in[1], d_in[3], d_in[5], d_in[7], d_in[9], d_in[11], d_in[13],
            d_in[2], d_in[4], d_in[6], d_in[8], d_in[10], d_in[12], d_in[14], d_in[15] };

    short* ws   = (short*)d_ws;
    short* qcat = ws;                     // R0: 8.4M bf16
    short* k1   = ws + 8388608;           // R1
    short* qp   = ws + 16777216;          // R2  q planar-T [b][c][w][h]
    short* kp   = ws + 25165824;          // R3  k planar   [b][c][h][w]
    short* vp   = ws + 33554432;          // R4  v planar   [b][c][h][w]
    short* wp   = ws + 41943040;          // packed weights (1,179,648)
    short* bb   = ws + 43122688;          // biases(1025) + pad + zeros(248 @ +1032)
    int*   flag = (int*)(ws + 43123968);
    short* xb   = qp;                     // x bf16; dead before qp written
    float* Et   = (float*)d_ws;           // aliases R0+R1 (dead after dispatch B)
    short* att  = qp;                     // aliases R2 (qp dead after energy)
    const short* zp = bb + 1032;          // 16-B-aligned zero block (496 B)

    detect_k<<<1, 256, 0, stream>>>((const short*)x, flag);
    convert_x<<<4096, 256, 0, stream>>>(x, xb, flag);
    convert_k<<<289, 256, 0, stream>>>(P, wp, bb, flag);

    // dispatch A: six x-reading convs, LONG (36-step) jobs first.
    // big jobs: 1024 blocks each; small: 256. All segment sizes %8==0.
    CJob j4{ xb, k1,   wp + 524288,  bb + 512, 256, 1, 9, 0,   0 };
    CJob j1{ xb, qcat, wp + 16384,   bb + 64,  64,  1, 9, 64,  0 };
    CJob j2{ xb, qcat, wp + 163840,  bb + 128, 64,  3, 9, 128, 0 };
    CJob j3{ xb, qcat, wp + 311296,  bb + 192, 64,  6, 9, 192, 0 };
    CJob jb{ xb, vp,   wp + 1114112, bb + 768, 256, 1, 1, 0,   2 };
    CJob ja{ xb, qcat, wp + 0,       bb + 0,   64,  1, 1, 0,   0 };
    CTable TA{ { j4, j1, j2, j3, jb, ja }, { 1024, 1280, 1536, 1792, 2816, 3072 } };
    conv_med<<<3072, 256, 0, stream>>>(TA, zp);

    // dispatch B: k = 3x3(k1) -> planar, then q = 1x1(qcat) -> planar-T
    CJob j6{ k1,   kp, wp + 524288, bb + 512, 256, 1, 9, 0, 2 };
    CJob j5{ qcat, qp, wp + 458752, bb + 256, 256, 1, 1, 0, 3 };
    CTable TB{ { j6, j5, j5, j5, j5, j5 }, { 1024, 2048, 2048, 2048, 2048, 2048 } };
    conv_med<<<2048, 256, 0, stream>>>(TB, zp);

    energy_mfma<<<512, 256, 0, stream>>>(qp, kp, Et);
    softmax_k<<<1024, 256, 0, stream>>>(Et, att);
    out_final<<<256, 512, 0, stream>>>(vp, att, x, d_in[15], d_out, flag);
}